// Round 7
// baseline (763.589 us; speedup 1.0000x reference)
//
#include <hip/hip_runtime.h>
#include <hip/hip_bf16.h>
#include <math.h>

// Problem constants: T=2048, B=4096, IN_S=1, H=20, OUT_S=1
#define TT 2048
#define BB 4096
#define HH 20

typedef float v2f __attribute__((ext_vector_type(2)));

#define L2E 1.4426950408889634f  // log2(e)

__device__ __forceinline__ float rcp_fast(float x)  { return __builtin_amdgcn_rcpf(x); }
__device__ __forceinline__ float exp2_fast(float x) { return __builtin_amdgcn_exp2f(x); }

__device__ __forceinline__ v2f pk_fma(v2f a, v2f b, v2f c) {
    return __builtin_elementwise_fma(a, b, c);
}
__device__ __forceinline__ v2f exp2v(v2f x) { v2f r; r.x = exp2_fast(x.x); r.y = exp2_fast(x.y); return r; }
__device__ __forceinline__ v2f rcpv(v2f x)  { v2f r; r.x = rcp_fast(x.x);  r.y = rcp_fast(x.y);  return r; }
__device__ __forceinline__ v2f absv(v2f x)  { v2f r; r.x = fabsf(x.x);     r.y = fabsf(x.y);     return r; }
__device__ __forceinline__ v2f csignv(v2f x, v2f s) {
    v2f r; r.x = copysignf(x.x, s.x); r.y = copysignf(x.y, s.y); return r;
}

// R15: same R14 structure (4 batches/wave, 2 units/lane, 1 wave/SIMD), but
// the dot is SPLIT INTO PRIORITY BLOCKS so the transcendental chain overlaps
// dot issue instead of running serially after it:
//   Block 1: g,f,i gates (60 pk_fma, 6-acc round robin) -> their hadds,
//     exp2s and the whole c-side chain (m1, num, rv, kn) become data-ready
//     while Block 2 (o-gate, 20 pk_fma) is still issuing. The o-gate result
//     is needed only for the FINAL mul (po*pc), so its tail is ~35cy.
// C-decomposition evidence (R14 counters): C=881cy = issue ~390 + LDS RT
// ~300 + ~190 latency tails. RT is structural (R13: bpermute worse; only
// ~30cy fillable during RT). Issue is near floor (80 pk_fma irreducible).
// This attacks the 190cy of tails. Pure reorder — no new instructions.
// R13 post-mortem: bpermute all-gather DEAD (+20cy per DS op on the chain).
// R12 post-mortem: weight-remat theory DEAD.
// Model: wall = T x C(chain); C is paid once per 4 batches (one wave/SIMD).
__global__ __launch_bounds__(64, 1) void lstm_fused_kernel(
    const float* __restrict__ u,      // [T, B, 1]
    const float* __restrict__ W_ih,   // [4H, 1]
    const float* __restrict__ W_hh,   // [4H, H]
    const float* __restrict__ W_out,  // [1, H]
    float* __restrict__ y)            // [T, B, 1]
{
    // hbuf[0..79]  = h for 4 batches x 20 units
    // hbuf[80..127] = scratch for y/idle lane writes (keeps the stream uniform)
    __shared__ __align__(16) float hbuf[128];

    const int lane = threadIdx.x;
    int q, wa, jbase;
    bool is_y = false;
    if (lane < 40) {
        q = lane / 10;
        const int p = lane - q * 10;
        wa = q * HH + 2 * p;          // write offset (floats), 8B-aligned
        jbase = 2 * p;
    } else {
        is_y = (lane < 44);
        q = is_y ? (lane - 40) : 0;   // y-lane reads its batch's h
        wa = 4 * HH + (lane - 40) * 2; // scratch area
        jbase = 0;
    }

    // h_{-1} = 0 everywhere.
    for (int i = lane; i < 128; i += 64) hbuf[i] = 0.0f;
    asm volatile("" ::: "memory");  // one-time, outside the hot loop

    // ---- Weights: per lane, rows (g, jbase) and (g, jbase+1), k-packed.
    // Pre-scaled into exp2 domain: i,f,o rows * -log2(e); g row * -2*log2(e).
    v2f wgv[4][2][10];
    v2f wihv[4][2];
    const float gsc[4] = {-L2E, -L2E, -2.0f * L2E, -L2E};
    #pragma unroll
    for (int g = 0; g < 4; ++g) {
        #pragma unroll
        for (int r = 0; r < 2; ++r) {
            const int row = g * HH + jbase + r;
            #pragma unroll
            for (int m = 0; m < 10; ++m) {
                wgv[g][r][m].x = gsc[g] * W_hh[row * HH + 2 * m];
                wgv[g][r][m].y = gsc[g] * W_hh[row * HH + 2 * m + 1];
            }
            wihv[g][r].x = gsc[g] * W_ih[row];
            wihv[g][r].y = 0.0f;
        }
    }
    if (lane >= 40) {  // y-lanes (idles too, harmless): gate0/r0 row := W_out
        #pragma unroll
        for (int m = 0; m < 10; ++m) {
            wgv[0][0][m].x = W_out[2 * m];      // UNSCALED: a[0][0] = dot(W_out, h)
            wgv[0][0][m].y = W_out[2 * m + 1];
        }
        wihv[0][0].x = 0.0f;                    // y has no u-term
    }

    // Keep final weight values as opaque defs (cheap insurance vs remat).
    #pragma unroll
    for (int g = 0; g < 4; ++g) {
        #pragma unroll
        for (int r = 0; r < 2; ++r) {
            #pragma unroll
            for (int m = 0; m < 10; ++m)
                asm volatile("" : "+v"(wgv[g][r][m].x), "+v"(wgv[g][r][m].y));
            asm volatile("" : "+v"(wihv[g][r].x));
        }
    }

    const v2f* hs = (const v2f*)&hbuf[q * HH];  // 16B-aligned (q*80 bytes)
    v2f* hw = (v2f*)&hbuf[wa];                  // no restrict: must alias hs

    v2f cv = {0.0f, 0.0f};
    const float* __restrict__ up = u + (size_t)blockIdx.x * 4 + q;
    float* yp = y + (size_t)blockIdx.x * 4 + (lane - 40);  // valid on y-lanes

    float u_cur[8];
    #pragma unroll
    for (int k = 0; k < 8; ++k) u_cur[k] = up[(size_t)k * BB];

    const v2f one = {1.0f, 1.0f};
    const v2f n2l2e = {-2.0f * L2E, -2.0f * L2E};

    for (int t8 = 0; t8 < TT; t8 += 8) {
        const int tn = (t8 + 8 < TT) ? (t8 + 8) : t8;
        float u_nxt[8];
        #pragma unroll
        for (int k = 0; k < 8; ++k) u_nxt[k] = up[(size_t)(tn + k) * BB];

        float y8[8];  // y-lanes: y8[tt] = y_{t8+tt-1} (gather sees h one step back)

        #pragma unroll
        for (int tt = 0; tt < 8; ++tt) {
            // ---- gather own batch's h_{t-1}: 5 x ds_read_b128 ----
            v2f h2[10];
            #pragma unroll
            for (int m = 0; m < 10; ++m) h2[m] = hs[m];

            const float uv = u_cur[tt];
            const v2f uv2 = {uv, uv};
            v2f a[4][2];
            #pragma unroll
            for (int g = 0; g < 4; ++g) {
                #pragma unroll
                for (int r = 0; r < 2; ++r) a[g][r] = wihv[g][r] * uv2;
            }

            // ---- DOT BLOCK 1: g,f,i gates (60 pk_fma, 6-acc round robin,
            // 12cy dep spacing). Their results feed the LONG trans chain. ----
            #pragma unroll
            for (int m = 0; m < 10; ++m) {
                const v2f hp = h2[m];
                a[2][0] = pk_fma(wgv[2][0][m], hp, a[2][0]);
                a[2][1] = pk_fma(wgv[2][1][m], hp, a[2][1]);
                a[1][0] = pk_fma(wgv[1][0][m], hp, a[1][0]);
                a[1][1] = pk_fma(wgv[1][1][m], hp, a[1][1]);
                a[0][0] = pk_fma(wgv[0][0][m], hp, a[0][0]);
                a[0][1] = pk_fma(wgv[0][1][m], hp, a[0][1]);
            }
            // g,f,i hadds + exp2s + c-side chain: data-ready NOW, so the
            // scheduler can interleave these with DOT BLOCK 2 below.
            v2f gi, gf, gg;
            gg.x = a[2][0].x + a[2][0].y;  gg.y = a[2][1].x + a[2][1].y;
            gf.x = a[1][0].x + a[1][0].y;  gf.y = a[1][1].x + a[1][1].y;
            gi.x = a[0][0].x + a[0][0].y;  gi.y = a[0][1].x + a[0][1].y;
            y8[tt] = gi.x;  // y-lanes: their a[0][0] is the W_out dot

            const v2f eg = exp2v(gg);   // e^{-2 x_g}
            const v2f ef = exp2v(gf);   // e^{-x_f}
            const v2f ei = exp2v(gi);   // e^{-x_i}
            const v2f pg = one + eg, pf = one + ef, pi2 = one + ei;
            const v2f mg = one - eg;    // tanh(x_g) sign falls out naturally

            // c' = f*c + i*tanh(g), one rcp; c retires OFF the h-path
            // (|c'| = |num|*rv, sign(c')=sign(num) since den>0).
            const v2f m1  = pg * pi2;
            const v2f num = pk_fma(cv, m1, mg * pf);
            const v2f rv  = rcpv(pf * m1);
            cv = num * rv;                                // next step only
            const v2f kn  = absv(num) * n2l2e;            // overlaps the rcp
            const v2f ec  = exp2v(kn * rv);               // e^{-2|c|} <= 1
            const v2f pc  = one + ec;
            const v2f mcs = csignv(one - ec, num);        // sign(c)==sign(num)

            // ---- DOT BLOCK 2: o-gate (20 pk_fma) — needed only for the
            // FINAL mul, so its ~35cy tail is the only exposed latency. ----
            #pragma unroll
            for (int m = 0; m < 10; ++m) {
                const v2f hp = h2[m];
                a[3][0] = pk_fma(wgv[3][0][m], hp, a[3][0]);
                a[3][1] = pk_fma(wgv[3][1][m], hp, a[3][1]);
            }
            v2f go;
            go.x = a[3][0].x + a[3][0].y;  go.y = a[3][1].x + a[3][1].y;
            const v2f eo = exp2v(go);   // e^{-x_o}
            const v2f po = one + eo;
            const v2f hv = mcs * rcpv(po * pc);

            // ---- publish h_t: one ds_write_b64 (compiler orders vs gather) ----
            *hw = hv;
        }

        if (is_y) {
            #pragma unroll
            for (int k = 0; k < 8; ++k) {
                const int idx = t8 - 1 + k;
                if (idx >= 0) yp[(size_t)idx * BB] = y8[k];
            }
        }

        #pragma unroll
        for (int k = 0; k < 8; ++k) u_cur[k] = u_nxt[k];
    }

    // Epilogue: y_{T-1} from the final h (y-lanes only).
    {
        v2f ay = {0.0f, 0.0f};
        #pragma unroll
        for (int m = 0; m < 10; ++m) ay = pk_fma(wgv[0][0][m], hs[m], ay);
        if (is_y) yp[(size_t)(TT - 1) * BB] = ay.x + ay.y;
    }
}

extern "C" void kernel_launch(void* const* d_in, const int* in_sizes, int n_in,
                              void* d_out, int out_size, void* d_ws, size_t ws_size,
                              hipStream_t stream) {
    const float* u     = (const float*)d_in[0];   // [2048, 4096, 1]
    const float* W_ih  = (const float*)d_in[1];   // [80, 1]
    const float* W_hh  = (const float*)d_in[2];   // [80, 20]
    const float* W_out = (const float*)d_in[3];   // [1, 20]
    float* y = (float*)d_out;                      // [2048, 4096, 1]

    const int blocks = BB / 4;  // 4 batches per single-wave block -> 1024 = 1 wave/SIMD
    lstm_fused_kernel<<<dim3(blocks), dim3(64), 0, stream>>>(u, W_ih, W_hh, W_out, y);
}

// Round 8
// 742.615 us; speedup vs baseline: 1.0282x; 1.0282x over previous
//
#include <hip/hip_runtime.h>
#include <hip/hip_bf16.h>
#include <math.h>

// Problem constants: T=2048, B=4096, IN_S=1, H=20, OUT_S=1
#define TT 2048
#define BB 4096
#define HH 20

typedef float v2f __attribute__((ext_vector_type(2)));

#define L2E 1.4426950408889634f  // log2(e)

__device__ __forceinline__ float rcp_fast(float x)  { return __builtin_amdgcn_rcpf(x); }
__device__ __forceinline__ float exp2_fast(float x) { return __builtin_amdgcn_exp2f(x); }

__device__ __forceinline__ v2f pk_fma(v2f a, v2f b, v2f c) {
    return __builtin_elementwise_fma(a, b, c);
}
__device__ __forceinline__ v2f exp2v(v2f x) { v2f r; r.x = exp2_fast(x.x); r.y = exp2_fast(x.y); return r; }
__device__ __forceinline__ v2f rcpv(v2f x)  { v2f r; r.x = rcp_fast(x.x);  r.y = rcp_fast(x.y);  return r; }
__device__ __forceinline__ v2f absv(v2f x)  { v2f r; r.x = fabsf(x.x);     r.y = fabsf(x.y);     return r; }
__device__ __forceinline__ v2f csignv(v2f x, v2f s) {
    v2f r; r.x = copysignf(x.x, s.x); r.y = copysignf(x.y, s.y); return r;
}

// R16: R14 structure (4 batches/wave, 2 units/lane, 1 wave/SIMD, 752us) with
// ONE change: the weight pins moved INSIDE the t8 loop.
// Why: VALUBusy=72% of C=881cy implies ~630cy VALU issue/step, but the
// visible instruction count is only ~466cy (80 pk_fma=160, 14 trans@quarter
// rate=224, ~35 v2f misc=70, DS=12). The ~160cy gap matches one hidden cost:
// per-lane weights (168 floats) > VGPR_Count=124, so the compiler parked
// them in AGPRs — and if v_pk_fma can't source AGPRs, each FMA needs a
// v_accvgpr_read first (~80 moves x 2cy = 160cy/step). An in-loop "+v" pin
// forces arch-VGPR residency across the hot loop in every world:
//   - AGPR-parked w/ per-use moves -> moves vanish (-160cy/step, big win)
//   - already free -> pin costs <=20cy/step of t8-boundary copies (noise)
// Either way VGPR_Count must jump to ~240 (the confirmation signal).
// R15 post-mortem: source reorder inside one basic block is a NO-OP — the
// scheduler already sees the whole dataflow graph. Reverted to R14 order.
// R13 post-mortem: bpermute all-gather DEAD. R12: out-of-loop pins DEAD
// (force VGPR class only at the pin point; regalloc re-parks for the loop).
// Model: wall = T x C(chain); C paid once per 4 batches (one wave/SIMD).
__global__ __launch_bounds__(64, 1) void lstm_fused_kernel(
    const float* __restrict__ u,      // [T, B, 1]
    const float* __restrict__ W_ih,   // [4H, 1]
    const float* __restrict__ W_hh,   // [4H, H]
    const float* __restrict__ W_out,  // [1, H]
    float* __restrict__ y)            // [T, B, 1]
{
    // hbuf[0..79]  = h for 4 batches x 20 units
    // hbuf[80..127] = scratch for y/idle lane writes (keeps the stream uniform)
    __shared__ __align__(16) float hbuf[128];

    const int lane = threadIdx.x;
    int q, wa, jbase;
    bool is_y = false;
    if (lane < 40) {
        q = lane / 10;
        const int p = lane - q * 10;
        wa = q * HH + 2 * p;          // write offset (floats), 8B-aligned
        jbase = 2 * p;
    } else {
        is_y = (lane < 44);
        q = is_y ? (lane - 40) : 0;   // y-lane reads its batch's h
        wa = 4 * HH + (lane - 40) * 2; // scratch area
        jbase = 0;
    }

    // h_{-1} = 0 everywhere.
    for (int i = lane; i < 128; i += 64) hbuf[i] = 0.0f;
    asm volatile("" ::: "memory");  // one-time, outside the hot loop

    // ---- Weights: per lane, rows (g, jbase) and (g, jbase+1), k-packed.
    // Pre-scaled into exp2 domain: i,f,o rows * -log2(e); g row * -2*log2(e).
    v2f wgv[4][2][10];
    v2f wihv[4][2];
    const float gsc[4] = {-L2E, -L2E, -2.0f * L2E, -L2E};
    #pragma unroll
    for (int g = 0; g < 4; ++g) {
        #pragma unroll
        for (int r = 0; r < 2; ++r) {
            const int row = g * HH + jbase + r;
            #pragma unroll
            for (int m = 0; m < 10; ++m) {
                wgv[g][r][m].x = gsc[g] * W_hh[row * HH + 2 * m];
                wgv[g][r][m].y = gsc[g] * W_hh[row * HH + 2 * m + 1];
            }
            wihv[g][r].x = gsc[g] * W_ih[row];
            wihv[g][r].y = 0.0f;
        }
    }
    if (lane >= 40) {  // y-lanes (idles too, harmless): gate0/r0 row := W_out
        #pragma unroll
        for (int m = 0; m < 10; ++m) {
            wgv[0][0][m].x = W_out[2 * m];      // UNSCALED: a[0][0] = dot(W_out, h)
            wgv[0][0][m].y = W_out[2 * m + 1];
        }
        wihv[0][0].x = 0.0f;                    // y has no u-term
    }

    const v2f* hs = (const v2f*)&hbuf[q * HH];  // 16B-aligned (q*80 bytes)
    v2f* hw = (v2f*)&hbuf[wa];                  // no restrict: must alias hs

    v2f cv = {0.0f, 0.0f};
    const float* __restrict__ up = u + (size_t)blockIdx.x * 4 + q;
    float* yp = y + (size_t)blockIdx.x * 4 + (lane - 40);  // valid on y-lanes

    float u_cur[8];
    #pragma unroll
    for (int k = 0; k < 8; ++k) u_cur[k] = up[(size_t)k * BB];

    const v2f one = {1.0f, 1.0f};
    const v2f n2l2e = {-2.0f * L2E, -2.0f * L2E};

    for (int t8 = 0; t8 < TT; t8 += 8) {
        // ---- IN-LOOP PIN: weights must be live in arch VGPRs here, every
        // iteration -> cannot be AGPR-parked (per-use moves) or remat'd
        // inside the hot loop. Cost if they were already fine: ~20cy/step.
        #pragma unroll
        for (int g = 0; g < 4; ++g) {
            #pragma unroll
            for (int r = 0; r < 2; ++r) {
                #pragma unroll
                for (int m = 0; m < 10; ++m)
                    asm volatile("" : "+v"(wgv[g][r][m].x), "+v"(wgv[g][r][m].y));
                asm volatile("" : "+v"(wihv[g][r].x));
            }
        }

        const int tn = (t8 + 8 < TT) ? (t8 + 8) : t8;
        float u_nxt[8];
        #pragma unroll
        for (int k = 0; k < 8; ++k) u_nxt[k] = up[(size_t)(tn + k) * BB];

        float y8[8];  // y-lanes: y8[tt] = y_{t8+tt-1} (gather sees h one step back)

        #pragma unroll
        for (int tt = 0; tt < 8; ++tt) {
            // ---- gather own batch's h_{t-1}: 5 x ds_read_b128 ----
            v2f h2[10];
            #pragma unroll
            for (int m = 0; m < 10; ++m) h2[m] = hs[m];

            const float uv = u_cur[tt];
            const v2f uv2 = {uv, uv};
            v2f a[4][2];
            #pragma unroll
            for (int g = 0; g < 4; ++g) {
                #pragma unroll
                for (int r = 0; r < 2; ++r) a[g][r] = wihv[g][r] * uv2;
            }

            // 80 v_pk_fma_f32; 8 accumulators round-robin -> 16cy dep spacing.
            #pragma unroll
            for (int m = 0; m < 10; ++m) {
                const v2f hp = h2[m];
                a[2][0] = pk_fma(wgv[2][0][m], hp, a[2][0]);
                a[2][1] = pk_fma(wgv[2][1][m], hp, a[2][1]);
                a[1][0] = pk_fma(wgv[1][0][m], hp, a[1][0]);
                a[1][1] = pk_fma(wgv[1][1][m], hp, a[1][1]);
                a[0][0] = pk_fma(wgv[0][0][m], hp, a[0][0]);
                a[0][1] = pk_fma(wgv[0][1][m], hp, a[0][1]);
                a[3][0] = pk_fma(wgv[3][0][m], hp, a[3][0]);
                a[3][1] = pk_fma(wgv[3][1][m], hp, a[3][1]);
            }
            // preacts packed (j0, j1) per gate
            v2f gi, gf, gg, go;
            gi.x = a[0][0].x + a[0][0].y;  gi.y = a[0][1].x + a[0][1].y;
            gf.x = a[1][0].x + a[1][0].y;  gf.y = a[1][1].x + a[1][1].y;
            gg.x = a[2][0].x + a[2][0].y;  gg.y = a[2][1].x + a[2][1].y;
            go.x = a[3][0].x + a[3][0].y;  go.y = a[3][1].x + a[3][1].y;
            y8[tt] = gi.x;  // y-lanes: their a[0][0] is the W_out dot

            // ---- activations, v2f (two independent j-chains interleave):
            // 10 exp2 + 4 rcp per lane, merged denominators (R9/R10 algebra).
            const v2f eg = exp2v(gg);   // e^{-2 x_g}
            const v2f ef = exp2v(gf);   // e^{-x_f}
            const v2f ei = exp2v(gi);   // e^{-x_i}
            const v2f eo = exp2v(go);   // e^{-x_o}
            const v2f pg = one + eg, pf = one + ef, pi2 = one + ei, po = one + eo;
            const v2f mg = one - eg;    // tanh(x_g) sign falls out naturally

            const v2f m1  = pg * pi2;
            const v2f num = pk_fma(cv, m1, mg * pf);
            const v2f rv  = rcpv(pf * m1);
            cv = num * rv;                                // next step only
            const v2f kn  = absv(num) * n2l2e;            // overlaps the rcp
            const v2f ec  = exp2v(kn * rv);               // e^{-2|c|} <= 1
            const v2f pc  = one + ec;
            const v2f mcs = csignv(one - ec, num);        // sign(c)==sign(num)
            const v2f hv  = mcs * rcpv(po * pc);

            // ---- publish h_t: one ds_write_b64 (compiler orders vs gather) ----
            *hw = hv;
        }

        if (is_y) {
            #pragma unroll
            for (int k = 0; k < 8; ++k) {
                const int idx = t8 - 1 + k;
                if (idx >= 0) yp[(size_t)idx * BB] = y8[k];
            }
        }

        #pragma unroll
        for (int k = 0; k < 8; ++k) u_cur[k] = u_nxt[k];
    }

    // Epilogue: y_{T-1} from the final h (y-lanes only).
    {
        v2f ay = {0.0f, 0.0f};
        #pragma unroll
        for (int m = 0; m < 10; ++m) ay = pk_fma(wgv[0][0][m], hs[m], ay);
        if (is_y) yp[(size_t)(TT - 1) * BB] = ay.x + ay.y;
    }
}

extern "C" void kernel_launch(void* const* d_in, const int* in_sizes, int n_in,
                              void* d_out, int out_size, void* d_ws, size_t ws_size,
                              hipStream_t stream) {
    const float* u     = (const float*)d_in[0];   // [2048, 4096, 1]
    const float* W_ih  = (const float*)d_in[1];   // [80, 1]
    const float* W_hh  = (const float*)d_in[2];   // [80, 20]
    const float* W_out = (const float*)d_in[3];   // [1, 20]
    float* y = (float*)d_out;                      // [2048, 4096, 1]

    const int blocks = BB / 4;  // 4 batches per single-wave block -> 1024 = 1 wave/SIMD
    lstm_fused_kernel<<<dim3(blocks), dim3(64), 0, stream>>>(u, W_ih, W_hh, W_out, y);
}